// Round 3
// baseline (2304.347 us; speedup 1.0000x reference)
//
#include <hip/hip_runtime.h>
#include <stdint.h>
#include <stddef.h>

// ---- problem constants ----
#define TT   1024
#define BB   32
#define II   1024
#define HH   1024
#define NHH  8
#define HSS  128
#define N4   4096   // NH*4*HS

typedef _Float16 h8 __attribute__((ext_vector_type(8)));
typedef _Float16 h4 __attribute__((ext_vector_type(4)));
typedef float    f4 __attribute__((ext_vector_type(4)));

// async global->LDS, 16B per lane. LDS dest is wave-uniform base + lane*16.
#define GLDS16(G, L) __builtin_amdgcn_global_load_lds(                      \
    (__attribute__((address_space(1))) void*)(G),                           \
    (__attribute__((address_space(3))) void*)(L), 16, 0, 0)

// ---------------- prep: zero states ----------------
__global__ void prep_kernel(float* __restrict__ st, float* __restrict__ hst) {
  int idx = blockIdx.x * blockDim.x + threadIdx.x;
  int stride = gridDim.x * blockDim.x;
  for (int i = idx; i < 3 * BB * NHH * HSS; i += stride) st[i] = 0.0f;
  for (int i = idx; i < BB * NHH * HSS; i += stride) hst[i] = 0.0f;
}

// ---------------- fp32 -> fp16 hi/lo split (lo pre-scaled by 2^11) ----------
// a = hi + lo/2048 with |err| ~ 2^-23 |a|. Scaling keeps lo in fp16 normal range.
__global__ __launch_bounds__(256) void convert_split(
    const float* __restrict__ src, _Float16* __restrict__ hi,
    _Float16* __restrict__ lo, int n4) {
  int idx = blockIdx.x * blockDim.x + threadIdx.x;
  int stride = gridDim.x * blockDim.x;
  for (int i = idx; i < n4; i += stride) {
    const float4 x = *(const float4*)&src[(size_t)i * 4];
    _Float16 h0 = (_Float16)x.x, h1 = (_Float16)x.y,
             h2 = (_Float16)x.z, h3 = (_Float16)x.w;
    _Float16 l0 = (_Float16)((x.x - (float)h0) * 2048.0f);
    _Float16 l1 = (_Float16)((x.y - (float)h1) * 2048.0f);
    _Float16 l2 = (_Float16)((x.z - (float)h2) * 2048.0f);
    _Float16 l3 = (_Float16)((x.w - (float)h3) * 2048.0f);
    h4 hv = {h0, h1, h2, h3};
    h4 lv = {l0, l1, l2, l3};
    *(h4*)&hi[(size_t)i * 4] = hv;
    *(h4*)&lo[(size_t)i * 4] = lv;
  }
}

// ---------------- gates GEMM via split-fp16 MFMA (unchanged, verified) ------
__global__ __launch_bounds__(256, 2) void gemm_gates_mfma(
    const _Float16* __restrict__ Ah, const _Float16* __restrict__ Al,
    const _Float16* __restrict__ Bh, const _Float16* __restrict__ Bl,
    const float* __restrict__ bias, float* __restrict__ C) {
  __shared__ __align__(16) _Float16 sAh[128 * 32];
  __shared__ __align__(16) _Float16 sAl[128 * 32];
  __shared__ __align__(16) _Float16 sBh[128 * 32];
  __shared__ __align__(16) _Float16 sBl[128 * 32];

  const int tid = threadIdx.x;
  const int lane = tid & 63;
  const int wave = tid >> 6;
  const long r0 = (long)blockIdx.y * 128;
  const long c0 = (long)blockIdx.x * 128;
  const int wr = (wave >> 1) * 64;
  const int wc = (wave & 1) * 64;

  f4 acc1[4][4], acc2[4][4];
#pragma unroll
  for (int i = 0; i < 4; ++i)
#pragma unroll
    for (int j = 0; j < 4; ++j) { acc1[i][j] = (f4)0.0f; acc2[i][j] = (f4)0.0f; }

  const int sRow = tid >> 2;
  const int sKh = (tid & 3) * 8;
  const _Float16* gAh = Ah + (r0 + sRow) * 1024 + sKh;
  const _Float16* gAl = Al + (r0 + sRow) * 1024 + sKh;
  const _Float16* gBh = Bh + (c0 + sRow) * 1024 + sKh;
  const _Float16* gBl = Bl + (c0 + sRow) * 1024 + sKh;
  _Float16* lAh = &sAh[sRow * 32 + sKh];
  _Float16* lAl = &sAl[sRow * 32 + sKh];
  _Float16* lBh = &sBh[sRow * 32 + sKh];
  _Float16* lBl = &sBl[sRow * 32 + sKh];

  const int fRow = lane & 15;
  const int fK = (lane >> 4) * 8;

  for (int kt = 0; kt < 32; ++kt) {
    const int k0 = kt * 32;
    GLDS16(gAh + k0, lAh);
    GLDS16(gAh + k0 + 64 * 1024, lAh + 64 * 32);
    GLDS16(gAl + k0, lAl);
    GLDS16(gAl + k0 + 64 * 1024, lAl + 64 * 32);
    GLDS16(gBh + k0, lBh);
    GLDS16(gBh + k0 + 64 * 1024, lBh + 64 * 32);
    GLDS16(gBl + k0, lBl);
    GLDS16(gBl + k0 + 64 * 1024, lBl + 64 * 32);
    __syncthreads();

    h8 fBh[4], fBl[4];
#pragma unroll
    for (int j = 0; j < 4; ++j) {
      fBh[j] = *(const h8*)&sBh[(wc + j * 16 + fRow) * 32 + fK];
      fBl[j] = *(const h8*)&sBl[(wc + j * 16 + fRow) * 32 + fK];
    }
#pragma unroll
    for (int i = 0; i < 4; ++i) {
      h8 ah = *(const h8*)&sAh[(wr + i * 16 + fRow) * 32 + fK];
      h8 al = *(const h8*)&sAl[(wr + i * 16 + fRow) * 32 + fK];
#pragma unroll
      for (int j = 0; j < 4; ++j) {
        acc1[i][j] = __builtin_amdgcn_mfma_f32_16x16x32_f16(ah, fBh[j], acc1[i][j], 0, 0, 0);
        acc2[i][j] = __builtin_amdgcn_mfma_f32_16x16x32_f16(ah, fBl[j], acc2[i][j], 0, 0, 0);
        acc2[i][j] = __builtin_amdgcn_mfma_f32_16x16x32_f16(al, fBh[j], acc2[i][j], 0, 0, 0);
      }
    }
    __syncthreads();
  }

  const int rgrp = (lane >> 4) * 4;
#pragma unroll
  for (int j = 0; j < 4; ++j) {
    const long col = c0 + wc + j * 16 + fRow;
    const float bj = bias[col];
#pragma unroll
    for (int i = 0; i < 4; ++i) {
      const long row = r0 + wr + i * 16 + rgrp;
#pragma unroll
      for (int q = 0; q < 4; ++q) {
        C[(row + q) * (long)N4 + col] =
            acc1[i][j][q] + acc2[i][j][q] * (1.0f / 2048.0f) + bj;
      }
    }
  }
}

// ---------------- sequential scan via M=1 MFMA matvec ----------------
// 256 blocks = head*32 + b, 8 waves. Wave w owns d-slice [16w,16w+16) and the
// four gate n-tiles {g*128 + 16w} (g=0..3) -> elementwise is wave-local in
// C-row 0 (lanes 0..15, reg q=0). W_hh resident as split-fp16 B-frags
// (4 gates x 4 ktiles x hi/lo = 128 VGPRs; AGPR placement fine for MFMA).
// h crosses steps via a double-buffered 2x256B split-fp16 LDS buffer:
// per step only 64 ds_read_b128 (vs 256 in the VALU version -> LDS-bound fix).
__device__ __forceinline__ float fast_sigmoid(float x) {
  return 1.0f / (1.0f + __expf(-x));
}
__device__ __forceinline__ float fast_tanh(float x) {
  return 1.0f - 2.0f / (__expf(2.0f * x) + 1.0f);
}

__global__ __launch_bounds__(512, 2) void scan_mfma(
    const float* __restrict__ gates, const _Float16* __restrict__ whh_hi,
    const _Float16* __restrict__ whh_lo, float* __restrict__ out,
    float* __restrict__ stc, float* __restrict__ stn, float* __restrict__ stm,
    float* __restrict__ hst, int t0, int chp) {
  __shared__ __align__(16) _Float16 hbuf[2][2][128];  // [buf][hi|lo][d]
  const int tid = threadIdx.x;
  const int lane = tid & 63;
  const int w = tid >> 6;
  const int head = blockIdx.x >> 5, b = blockIdx.x & 31;
  const int fcol = lane & 15;        // d offset within slice / C col
  const int fk = (lane >> 4) * 8;    // k offset within 32-k tile
  const int d = w * 16 + fcol;
  const bool owner = (lane < 16);

  // resident B-fragments: whh[head][n][k], n = g*128 + d, k = kt*32 + fk
  h8 Bh[4][4], Bl[4][4];
#pragma unroll
  for (int g = 0; g < 4; ++g)
#pragma unroll
    for (int kt = 0; kt < 4; ++kt) {
      const size_t off = ((size_t)((head * 4 + g) * 128 + d)) * 128 + kt * 32 + fk;
      Bh[g][kt] = *(const h8*)&whh_hi[off];
      Bl[g][kt] = *(const h8*)&whh_lo[off];
    }

  float c = 0.f, nn = 0.f, m = 0.f, hlast = 0.f;
  const int si = (b * NHH + head) * HSS + d;
  if (owner) {
    c = stc[si]; nn = stn[si]; m = stm[si];
    float h0 = hst[si];
    hlast = h0;
    _Float16 hh = (_Float16)h0;
    _Float16 hl = (_Float16)((h0 - (float)hh) * 2048.0f);
    hbuf[0][0][d] = hh;
    hbuf[0][1][d] = hl;
  }
  __syncthreads();

  // gate preactivation stream: row = t*32 + b, col = head*512 + g*128 + d
  const float* gptr = gates + (size_t)b * N4 + head * 512 + d;
  float gc[4] = {0.f, 0.f, 0.f, 0.f};
  if (owner) {
#pragma unroll
    for (int g = 0; g < 4; ++g) gc[g] = gptr[g * 128];
  }

  int cur = 0;
  for (int t = 0; t < chp; ++t) {
    // A-fragments: h split-fp16 broadcast (rows 1..15 get copies; C rows
    // 1..15 are garbage and never read -- rows are independent in MFMA)
    h8 Ah[4], Al[4];
#pragma unroll
    for (int kt = 0; kt < 4; ++kt) {
      Ah[kt] = *(const h8*)&hbuf[cur][0][kt * 32 + fk];
      Al[kt] = *(const h8*)&hbuf[cur][1][kt * 32 + fk];
    }

    // prefetch next step's gate preactivations (latency hidden under MFMA)
    float gn[4] = {0.f, 0.f, 0.f, 0.f};
    if (owner && t + 1 < chp) {
      const float* gp = gptr + (size_t)(t + 1) * 32 * N4;
#pragma unroll
      for (int g = 0; g < 4; ++g) gn[g] = gp[g * 128];
    }

    f4 c1[4], c2[4];
#pragma unroll
    for (int g = 0; g < 4; ++g) {
      f4 z = (f4)0.0f;
      z[0] = owner ? gc[g] : 0.0f;   // seed C row0 with GEMM preact
      c1[g] = z;
      c2[g] = (f4)0.0f;
    }
#pragma unroll
    for (int kt = 0; kt < 4; ++kt)
#pragma unroll
      for (int g = 0; g < 4; ++g) {
        c1[g] = __builtin_amdgcn_mfma_f32_16x16x32_f16(Ah[kt], Bh[g][kt], c1[g], 0, 0, 0);
        c2[g] = __builtin_amdgcn_mfma_f32_16x16x32_f16(Ah[kt], Bl[g][kt], c2[g], 0, 0, 0);
        c2[g] = __builtin_amdgcn_mfma_f32_16x16x32_f16(Al[kt], Bh[g][kt], c2[g], 0, 0, 0);
      }

    if (owner) {
      const float k = 1.0f / 2048.0f;
      float pi = c1[0][0] + c2[0][0] * k;
      float pf = c1[1][0] + c2[1][0] * k;
      float pz = c1[2][0] + c2[2][0] * k;
      float po = c1[3][0] + c2[3][0] * k;
      float a = pf + m;
      float mn = fmaxf(a, pi);
      float fe = __expf(a - mn);
      float ie = __expf(pi - mn);
      float zt = fast_tanh(pz);
      float og = fast_sigmoid(po);
      c = fe * c + ie * zt;
      nn = fe * nn + ie;
      m = mn;
      float h = og * (c / nn);
      hlast = h;
      out[(size_t)(t0 + t) * (BB * HH) + (size_t)b * HH + head * HSS + d] = h;
      _Float16 hh = (_Float16)h;
      _Float16 hl = (_Float16)((h - (float)hh) * 2048.0f);
      hbuf[cur ^ 1][0][d] = hh;
      hbuf[cur ^ 1][1][d] = hl;
    }
    __syncthreads();
    cur ^= 1;
#pragma unroll
    for (int g = 0; g < 4; ++g) gc[g] = gn[g];
  }

  if (owner) {
    stc[si] = c; stn[si] = nn; stm[si] = m;
    hst[si] = hlast;
  }
}

// ---------------- launcher ----------------
// ws: stc/stn/stm/hst 128KB ea | whh_hi/lo 1MB ea | Bh/Bl (wih) 8MB ea |
//     Ah/Al ch*64KB ea | gates ch*512KB
extern "C" void kernel_launch(void* const* d_in, const int* in_sizes, int n_in,
                              void* d_out, int out_size, void* d_ws, size_t ws_size,
                              hipStream_t stream) {
  const float* xs   = (const float*)d_in[0];
  const float* wih  = (const float*)d_in[1];
  const float* whh  = (const float*)d_in[2];
  const float* bias = (const float*)d_in[3];
  float* out = (float*)d_out;
  char* ws = (char*)d_ws;

  float* stc = (float*)(ws + 0);
  float* stn = (float*)(ws + 131072);
  float* stm = (float*)(ws + 262144);
  float* hst = (float*)(ws + 393216);
  _Float16* Whi = (_Float16*)(ws + 524288);    // 8*512*128*2 = 1048576
  _Float16* Wlo = (_Float16*)(ws + 1572864);
  _Float16* Bh  = (_Float16*)(ws + 2621440);   // 4096*1024*2 = 8388608
  _Float16* Bl  = (_Float16*)(ws + 11010048);  // ends 19398656
  const size_t base = 19398656;

  // per-chunk: Ah + Al = ch*131072 B, gates = ch*524288 B
  int ch = 256;
  while (ch > 8 && base + (size_t)ch * 655360 > ws_size) ch >>= 1;
  _Float16* Ahp = (_Float16*)(ws + base);
  _Float16* Alp = (_Float16*)(ws + base + (size_t)ch * 65536);
  float* gts = (float*)(ws + base + (size_t)ch * 131072);
  const int nch = TT / ch;

  prep_kernel<<<256, 256, 0, stream>>>(stc, hst);
  convert_split<<<1024, 256, 0, stream>>>(whh, Whi, Wlo, NHH * 512 * HSS / 4);
  convert_split<<<1024, 256, 0, stream>>>(wih, Bh, Bl, N4 * II / 4);

  for (int cix = 0; cix < nch; ++cix) {
    convert_split<<<1024, 256, 0, stream>>>(xs + (size_t)cix * ch * BB * II,
                                            Ahp, Alp, ch * BB * II / 4);
    dim3 g(32, (unsigned)(ch * 32 / 128));
    gemm_gates_mfma<<<g, 256, 0, stream>>>(Ahp, Alp, Bh, Bl, bias, gts);
    scan_mfma<<<256, 512, 0, stream>>>(gts, Whi, Wlo, out, stc, stn, stm, hst,
                                       cix * ch, ch);
  }
}

// Round 4
// 2132.821 us; speedup vs baseline: 1.0804x; 1.0804x over previous
//
#include <hip/hip_runtime.h>
#include <stdint.h>
#include <stddef.h>

// ---- problem constants ----
#define TT   1024
#define BB   32
#define II   1024
#define HH   1024
#define NHH  8
#define HSS  128
#define N4   4096   // NH*4*HS

typedef _Float16 h8 __attribute__((ext_vector_type(8)));
typedef _Float16 h4 __attribute__((ext_vector_type(4)));
typedef float    f4 __attribute__((ext_vector_type(4)));

// async global->LDS, 16B per lane. LDS dest is wave-uniform base + lane*16.
#define GLDS16(G, L) __builtin_amdgcn_global_load_lds(                      \
    (__attribute__((address_space(1))) void*)(G),                           \
    (__attribute__((address_space(3))) void*)(L), 16, 0, 0)

// workgroup barrier WITHOUT the vmcnt(0) drain __syncthreads() would emit.
// lgkmcnt(0) makes this wave's LDS writes visible; global loads/stores stay
// in flight across the barrier (consumption sites get counted vmcnt waits).
#define BARRIER_LDS_ONLY() asm volatile("s_waitcnt lgkmcnt(0)\n\ts_barrier" ::: "memory")

// ---------------- prep: zero states ----------------
__global__ void prep_kernel(float* __restrict__ st, float* __restrict__ hst) {
  int idx = blockIdx.x * blockDim.x + threadIdx.x;
  int stride = gridDim.x * blockDim.x;
  for (int i = idx; i < 3 * BB * NHH * HSS; i += stride) st[i] = 0.0f;
  for (int i = idx; i < BB * NHH * HSS; i += stride) hst[i] = 0.0f;
}

// ---------------- fp32 -> fp16 hi/lo split (lo pre-scaled by 2^11) ----------
// a = hi + lo/2048 with |err| ~ 2^-23 |a|. Scaling keeps lo in fp16 normal range.
__global__ __launch_bounds__(256) void convert_split(
    const float* __restrict__ src, _Float16* __restrict__ hi,
    _Float16* __restrict__ lo, int n4) {
  int idx = blockIdx.x * blockDim.x + threadIdx.x;
  int stride = gridDim.x * blockDim.x;
  for (int i = idx; i < n4; i += stride) {
    const float4 x = *(const float4*)&src[(size_t)i * 4];
    _Float16 h0 = (_Float16)x.x, h1 = (_Float16)x.y,
             h2 = (_Float16)x.z, h3 = (_Float16)x.w;
    _Float16 l0 = (_Float16)((x.x - (float)h0) * 2048.0f);
    _Float16 l1 = (_Float16)((x.y - (float)h1) * 2048.0f);
    _Float16 l2 = (_Float16)((x.z - (float)h2) * 2048.0f);
    _Float16 l3 = (_Float16)((x.w - (float)h3) * 2048.0f);
    h4 hv = {h0, h1, h2, h3};
    h4 lv = {l0, l1, l2, l3};
    *(h4*)&hi[(size_t)i * 4] = hv;
    *(h4*)&lo[(size_t)i * 4] = lv;
  }
}

// ---------------- gates GEMM via split-fp16 MFMA (unchanged, verified) ------
__global__ __launch_bounds__(256, 2) void gemm_gates_mfma(
    const _Float16* __restrict__ Ah, const _Float16* __restrict__ Al,
    const _Float16* __restrict__ Bh, const _Float16* __restrict__ Bl,
    const float* __restrict__ bias, float* __restrict__ C) {
  __shared__ __align__(16) _Float16 sAh[128 * 32];
  __shared__ __align__(16) _Float16 sAl[128 * 32];
  __shared__ __align__(16) _Float16 sBh[128 * 32];
  __shared__ __align__(16) _Float16 sBl[128 * 32];

  const int tid = threadIdx.x;
  const int lane = tid & 63;
  const int wave = tid >> 6;
  const long r0 = (long)blockIdx.y * 128;
  const long c0 = (long)blockIdx.x * 128;
  const int wr = (wave >> 1) * 64;
  const int wc = (wave & 1) * 64;

  f4 acc1[4][4], acc2[4][4];
#pragma unroll
  for (int i = 0; i < 4; ++i)
#pragma unroll
    for (int j = 0; j < 4; ++j) { acc1[i][j] = (f4)0.0f; acc2[i][j] = (f4)0.0f; }

  const int sRow = tid >> 2;
  const int sKh = (tid & 3) * 8;
  const _Float16* gAh = Ah + (r0 + sRow) * 1024 + sKh;
  const _Float16* gAl = Al + (r0 + sRow) * 1024 + sKh;
  const _Float16* gBh = Bh + (c0 + sRow) * 1024 + sKh;
  const _Float16* gBl = Bl + (c0 + sRow) * 1024 + sKh;
  _Float16* lAh = &sAh[sRow * 32 + sKh];
  _Float16* lAl = &sAl[sRow * 32 + sKh];
  _Float16* lBh = &sBh[sRow * 32 + sKh];
  _Float16* lBl = &sBl[sRow * 32 + sKh];

  const int fRow = lane & 15;
  const int fK = (lane >> 4) * 8;

  for (int kt = 0; kt < 32; ++kt) {
    const int k0 = kt * 32;
    GLDS16(gAh + k0, lAh);
    GLDS16(gAh + k0 + 64 * 1024, lAh + 64 * 32);
    GLDS16(gAl + k0, lAl);
    GLDS16(gAl + k0 + 64 * 1024, lAl + 64 * 32);
    GLDS16(gBh + k0, lBh);
    GLDS16(gBh + k0 + 64 * 1024, lBh + 64 * 32);
    GLDS16(gBl + k0, lBl);
    GLDS16(gBl + k0 + 64 * 1024, lBl + 64 * 32);
    __syncthreads();

    h8 fBh[4], fBl[4];
#pragma unroll
    for (int j = 0; j < 4; ++j) {
      fBh[j] = *(const h8*)&sBh[(wc + j * 16 + fRow) * 32 + fK];
      fBl[j] = *(const h8*)&sBl[(wc + j * 16 + fRow) * 32 + fK];
    }
#pragma unroll
    for (int i = 0; i < 4; ++i) {
      h8 ah = *(const h8*)&sAh[(wr + i * 16 + fRow) * 32 + fK];
      h8 al = *(const h8*)&sAl[(wr + i * 16 + fRow) * 32 + fK];
#pragma unroll
      for (int j = 0; j < 4; ++j) {
        acc1[i][j] = __builtin_amdgcn_mfma_f32_16x16x32_f16(ah, fBh[j], acc1[i][j], 0, 0, 0);
        acc2[i][j] = __builtin_amdgcn_mfma_f32_16x16x32_f16(ah, fBl[j], acc2[i][j], 0, 0, 0);
        acc2[i][j] = __builtin_amdgcn_mfma_f32_16x16x32_f16(al, fBh[j], acc2[i][j], 0, 0, 0);
      }
    }
    __syncthreads();
  }

  const int rgrp = (lane >> 4) * 4;
#pragma unroll
  for (int j = 0; j < 4; ++j) {
    const long col = c0 + wc + j * 16 + fRow;
    const float bj = bias[col];
#pragma unroll
    for (int i = 0; i < 4; ++i) {
      const long row = r0 + wr + i * 16 + rgrp;
#pragma unroll
      for (int q = 0; q < 4; ++q) {
        C[(row + q) * (long)N4 + col] =
            acc1[i][j][q] + acc2[i][j][q] * (1.0f / 2048.0f) + bj;
      }
    }
  }
}

// ---------------- sequential scan via M=1 MFMA matvec ----------------
// 256 blocks = head*32 + b, 8 waves. Wave w owns d-slice [16w,16w+16) and all
// four gate n-tiles -> elementwise is wave-local in C row 0 (lanes 0..15).
// W_hh resident as split-fp16 B-frags (AGPR-placed, MFMA reads natively).
// Round-4 changes: (1) barrier without vmcnt drain -- gate loads / out stores
// stay in flight across steps (round-3 post-mortem: __syncthreads' vmcnt(0)
// forced a full memory-latency round trip per step, pinning ~3400 cyc/step in
// both VALU and MFMA variants); (2) gate prefetch depth 4 via unroll-4
// rotating register buffer (static indexing).
__device__ __forceinline__ float fast_sigmoid(float x) {
  return 1.0f / (1.0f + __expf(-x));
}
__device__ __forceinline__ float fast_tanh(float x) {
  return 1.0f - 2.0f / (__expf(2.0f * x) + 1.0f);
}

__global__ __launch_bounds__(512, 2) void scan_mfma(
    const float* __restrict__ gates, const _Float16* __restrict__ whh_hi,
    const _Float16* __restrict__ whh_lo, float* __restrict__ out,
    float* __restrict__ stc, float* __restrict__ stn, float* __restrict__ stm,
    float* __restrict__ hst, int t0, int chp) {
  __shared__ __align__(16) _Float16 hbuf[2][2][128];  // [buf][hi|lo][d]
  const int tid = threadIdx.x;
  const int lane = tid & 63;
  const int w = tid >> 6;
  const int head = blockIdx.x >> 5, b = blockIdx.x & 31;
  const int fcol = lane & 15;        // d offset within slice / C col
  const int fk = (lane >> 4) * 8;    // k offset within 32-k tile
  const int d = w * 16 + fcol;
  const bool owner = (lane < 16);

  // resident B-fragments: whh[head][n][k], n = g*128 + d, k = kt*32 + fk
  h8 Bh[4][4], Bl[4][4];
#pragma unroll
  for (int g = 0; g < 4; ++g)
#pragma unroll
    for (int kt = 0; kt < 4; ++kt) {
      const size_t off = ((size_t)((head * 4 + g) * 128 + d)) * 128 + kt * 32 + fk;
      Bh[g][kt] = *(const h8*)&whh_hi[off];
      Bl[g][kt] = *(const h8*)&whh_lo[off];
    }

  float c = 0.f, nn = 0.f, m = 0.f, hlast = 0.f;
  const int si = (b * NHH + head) * HSS + d;
  if (owner) {
    c = stc[si]; nn = stn[si]; m = stm[si];
    float h0 = hst[si];
    hlast = h0;
    _Float16 hh = (_Float16)h0;
    _Float16 hl = (_Float16)((h0 - (float)hh) * 2048.0f);
    hbuf[0][0][d] = hh;
    hbuf[0][1][d] = hl;
  }
  __syncthreads();

  // gate preactivation stream: row = t*32 + b, col = head*512 + g*128 + d
  const float* gptr = gates + (size_t)b * N4 + head * 512 + d;

  // depth-4 rotating prefetch buffer (static slot indexing via unroll)
  float gb[4][4];
  if (owner) {
#pragma unroll
    for (int u = 0; u < 4; ++u) {
      const float* gp = gptr + (size_t)u * 32 * N4;   // chp >= 8 always
#pragma unroll
      for (int g = 0; g < 4; ++g) gb[u][g] = gp[g * 128];
    }
  }

  int cur = 0;
  for (int tb = 0; tb < chp; tb += 4) {
#pragma unroll
    for (int u = 0; u < 4; ++u) {
      const int t = tb + u;

      // A-fragments: h split-fp16 broadcast (C rows 1..15 garbage, never read)
      h8 Ah[4], Al[4];
#pragma unroll
      for (int kt = 0; kt < 4; ++kt) {
        Ah[kt] = *(const h8*)&hbuf[cur][0][kt * 32 + fk];
        Al[kt] = *(const h8*)&hbuf[cur][1][kt * 32 + fk];
      }

      // seed C row0 with GEMM preactivation (consumes gb[u])
      f4 c1[4], c2[4];
#pragma unroll
      for (int g = 0; g < 4; ++g) {
        f4 z = (f4)0.0f;
        z[0] = owner ? gb[u][g] : 0.0f;
        c1[g] = z;
        c2[g] = (f4)0.0f;
      }

      // re-issue slot u for step t+4 (3+ steps of latency cover, no drain)
      if (owner && t + 4 < chp) {
        const float* gp = gptr + (size_t)(t + 4) * 32 * N4;
#pragma unroll
        for (int g = 0; g < 4; ++g) gb[u][g] = gp[g * 128];
      }

#pragma unroll
      for (int kt = 0; kt < 4; ++kt)
#pragma unroll
        for (int g = 0; g < 4; ++g) {
          c1[g] = __builtin_amdgcn_mfma_f32_16x16x32_f16(Ah[kt], Bh[g][kt], c1[g], 0, 0, 0);
          c2[g] = __builtin_amdgcn_mfma_f32_16x16x32_f16(Ah[kt], Bl[g][kt], c2[g], 0, 0, 0);
          c2[g] = __builtin_amdgcn_mfma_f32_16x16x32_f16(Al[kt], Bh[g][kt], c2[g], 0, 0, 0);
        }

      if (owner) {
        const float k = 1.0f / 2048.0f;
        float pi = c1[0][0] + c2[0][0] * k;
        float pf = c1[1][0] + c2[1][0] * k;
        float pz = c1[2][0] + c2[2][0] * k;
        float po = c1[3][0] + c2[3][0] * k;
        float a = pf + m;
        float mn = fmaxf(a, pi);
        float fe = __expf(a - mn);
        float ie = __expf(pi - mn);
        float zt = fast_tanh(pz);
        float og = fast_sigmoid(po);
        c = fe * c + ie * zt;
        nn = fe * nn + ie;
        m = mn;
        float h = og * (c / nn);
        hlast = h;
        out[(size_t)(t0 + t) * (BB * HH) + (size_t)b * HH + head * HSS + d] = h;
        _Float16 hh = (_Float16)h;
        _Float16 hl = (_Float16)((h - (float)hh) * 2048.0f);
        hbuf[cur ^ 1][0][d] = hh;
        hbuf[cur ^ 1][1][d] = hl;
      }
      BARRIER_LDS_ONLY();
      cur ^= 1;
    }
  }

  if (owner) {
    stc[si] = c; stn[si] = nn; stm[si] = m;
    hst[si] = hlast;
  }
}

// ---------------- launcher ----------------
// ws: stc/stn/stm/hst 128KB ea | whh_hi/lo 1MB ea | Bh/Bl (wih) 8MB ea |
//     Ah/Al ch*64KB ea | gates ch*512KB
extern "C" void kernel_launch(void* const* d_in, const int* in_sizes, int n_in,
                              void* d_out, int out_size, void* d_ws, size_t ws_size,
                              hipStream_t stream) {
  const float* xs   = (const float*)d_in[0];
  const float* wih  = (const float*)d_in[1];
  const float* whh  = (const float*)d_in[2];
  const float* bias = (const float*)d_in[3];
  float* out = (float*)d_out;
  char* ws = (char*)d_ws;

  float* stc = (float*)(ws + 0);
  float* stn = (float*)(ws + 131072);
  float* stm = (float*)(ws + 262144);
  float* hst = (float*)(ws + 393216);
  _Float16* Whi = (_Float16*)(ws + 524288);    // 8*512*128*2 = 1048576
  _Float16* Wlo = (_Float16*)(ws + 1572864);
  _Float16* Bh  = (_Float16*)(ws + 2621440);   // 4096*1024*2 = 8388608
  _Float16* Bl  = (_Float16*)(ws + 11010048);  // ends 19398656
  const size_t base = 19398656;

  // per-chunk: Ah + Al = ch*131072 B, gates = ch*524288 B
  int ch = 256;
  while (ch > 8 && base + (size_t)ch * 655360 > ws_size) ch >>= 1;
  _Float16* Ahp = (_Float16*)(ws + base);
  _Float16* Alp = (_Float16*)(ws + base + (size_t)ch * 65536);
  float* gts = (float*)(ws + base + (size_t)ch * 131072);
  const int nch = TT / ch;

  prep_kernel<<<256, 256, 0, stream>>>(stc, hst);
  convert_split<<<1024, 256, 0, stream>>>(whh, Whi, Wlo, NHH * 512 * HSS / 4);
  convert_split<<<1024, 256, 0, stream>>>(wih, Bh, Bl, N4 * II / 4);

  for (int cix = 0; cix < nch; ++cix) {
    convert_split<<<1024, 256, 0, stream>>>(xs + (size_t)cix * ch * BB * II,
                                            Ahp, Alp, ch * BB * II / 4);
    dim3 g(32, (unsigned)(ch * 32 / 128));
    gemm_gates_mfma<<<g, 256, 0, stream>>>(Ahp, Alp, Bh, Bl, bias, gts);
    scan_mfma<<<256, 512, 0, stream>>>(gts, Whi, Wlo, out, stc, stn, stm, hst,
                                       cix * ch, ch);
  }
}